// Round 10
// baseline (301.493 us; speedup 1.0000x reference)
//
#include <hip/hip_runtime.h>
#include <math.h>

#define ALPHA 0.01f
#define EPSF  1e-5f
#define NPRED 2048
#define MTARG 256
#define NT    256
#define CPT   8            // NPRED / NT
#define KMAX  512
#define SPT   2            // KMAX / NT
#define NW    4
#define MARGIN 0.041f      // alpha*4 (max geo term) + fp safety
#define BIGF  1e30f
#define EPSA  0.032f       // auction epsilon (bound 256*0.032 = 8.2 << 24.8)
#define MAXROUND 30000
#define IINF 0x7FFFFFFF
#define SLO   (-11.6f)     // s = log(1-c+e)-log(c+e) ∈ [-11.52, 11.52]
#define SRANGE 23.3f
#define SBINS 256

__device__ __forceinline__ unsigned int ordf(float v) {
  const unsigned int b = __float_as_uint(v);
  return (v >= 0.0f) ? (b | 0x80000000u) : ~b;
}
__device__ __forceinline__ float unordf(unsigned int u) {
  return __uint_as_float((u & 0x80000000u) ? (u & 0x7FFFFFFFu) : ~u);
}

__launch_bounds__(NT, 1)
__global__ void lap_loss_kernel(const float* __restrict__ pred,
                                const float* __restrict__ label,
                                float* __restrict__ out) {
  // kept columns (compacted), K <= KMAX
  __shared__ float4 s_k4[KMAX];      // pred coords
  __shared__ float  s_cc[KMAX];      // alpha*|p|^2 + s_j
  __shared__ float  s_cp[KMAX];      // cc + price
  __shared__ short  s_row4col[KMAX];
  __shared__ short  s_argr[KMAX];
  __shared__ int    s_bC[KMAX];      // greedy pass-A board
  // rows (targets)
  __shared__ float  s_u[MTARG];
  __shared__ short  s_col4row[MTARG];
  __shared__ float4 s_m2t[MTARG];    // -2*alpha*targ
  __shared__ float  s_rc[MTARG];     // alpha*|targ|^2
  __shared__ short  s_amin[MTARG];
  __shared__ int    s_bR[MTARG];     // greedy pass-B board
  // selection / scratch
  __shared__ int   s_hist[SBINS];
  __shared__ int   s_cnt[CPT * NW];  // kept counts per (k, wave)
  __shared__ float s_scr[NW];
  __shared__ float s_pivot, s_sumlca;
  __shared__ int   s_K;

  const int tid  = threadIdx.x;
  const int wave = tid >> 6;
  const int lane = tid & 63;
  const unsigned long long laneLT = (lane == 63) ? 0x7FFFFFFFFFFFFFFFull
                                                 : ((1ull << lane) - 1ull);
  const float* pbase = pred  + (size_t)15 * NPRED * 5;
  const float* lbase = label + (size_t)15 * MTARG * 4;

  s_hist[tid] = 0;
  __syncthreads();

  // ---------- phase 0: per-column s_j, histogram, sum lca ----------
  float mys[CPT];
  float lca_acc = 0.0f;
#pragma unroll
  for (int k = 0; k < CPT; ++k) {
    const int j = tid + k * NT;
    const float c = pbase[j * 5 + 4];
    const float lc  = logf(c + EPSF);
    const float lca = logf(1.0f - c + EPSF);
    mys[k] = lca - lc;
    lca_acc += lca;
    int b = (int)((mys[k] - SLO) * ((float)SBINS / SRANGE));
    b = b < 0 ? 0 : (b > SBINS - 1 ? SBINS - 1 : b);
    atomicAdd(&s_hist[b], 1);
  }
#pragma unroll
  for (int off = 32; off > 0; off >>= 1) lca_acc += __shfl_down(lca_acc, off);
  if (lane == 0) s_scr[wave] = lca_acc;
  __syncthreads();
  if (tid == 0) {
    float s = 0.0f;
    for (int w = 0; w < NW; ++w) s += s_scr[w];
    s_sumlca = s;
  }

  // ---------- phase 1: pivot = upper edge of bin where cumcount crosses 256 ----------
  if (tid < 64) {
    const int4 h = *(const int4*)&s_hist[tid * 4];
    const int loc = h.x + h.y + h.z + h.w;
    int scan = loc;
#pragma unroll
    for (int off = 1; off < 64; off <<= 1) {
      const int o = __shfl_up(scan, off);
      if (lane >= off) scan += o;
    }
    int c = scan - loc;          // exclusive prefix
    int cb = IINF;
    c += h.x; if (cb == IINF && c >= MTARG) cb = 4 * tid + 0;
    c += h.y; if (cb == IINF && c >= MTARG) cb = 4 * tid + 1;
    c += h.z; if (cb == IINF && c >= MTARG) cb = 4 * tid + 2;
    c += h.w; if (cb == IINF && c >= MTARG) cb = 4 * tid + 3;
#pragma unroll
    for (int off = 1; off < 64; off <<= 1) {
      const int o = __shfl_xor(cb, off);
      if (o < cb) cb = o;
    }
    if (lane == 0) s_pivot = SLO + (float)(cb + 1) * (SRANGE / (float)SBINS);
  }
  __syncthreads();

  // ---------- phase 2: deterministic ballot-prefix compaction ----------
  const float keepThr = s_pivot + MARGIN;
  unsigned long long km[CPT];
#pragma unroll
  for (int k = 0; k < CPT; ++k) {
    km[k] = __ballot(mys[k] <= keepThr);
    if (lane == 0) s_cnt[k * NW + wave] = (int)__popcll(km[k]);
  }
#pragma unroll
  for (int k = 0; k < SPT; ++k) s_bC[tid + k * NT] = IINF;
  {
    const float* t = lbase + tid * 4;
    const float tx = t[0], ty = t[1], tz = t[2], tw = t[3];
    s_m2t[tid] = make_float4(-2.0f*ALPHA*tx, -2.0f*ALPHA*ty, -2.0f*ALPHA*tz, -2.0f*ALPHA*tw);
    s_rc[tid]  = ALPHA * (tx*tx + ty*ty + tz*tz + tw*tw);
    s_col4row[tid] = -1;
    s_bR[tid] = IINF;
  }
  __syncthreads();
  {
    int cnts[CPT][NW];
#pragma unroll
    for (int k = 0; k < CPT; ++k)
#pragma unroll
      for (int w = 0; w < NW; ++w) cnts[k][w] = s_cnt[k * NW + w];
    int pre = 0;
    int Ktot = 0;
#pragma unroll
    for (int k = 0; k < CPT; ++k)
#pragma unroll
      for (int w = 0; w < NW; ++w) Ktot += cnts[k][w];
#pragma unroll
    for (int k = 0; k < CPT; ++k) {
      int base = pre;
#pragma unroll
      for (int w = 0; w < NW; ++w) { if (w < wave) base += cnts[k][w]; pre += cnts[k][w]; }
      if (mys[k] <= keepThr) {
        const int slot = base + (int)__popcll(km[k] & laneLT);
        if (slot < KMAX) {
          const int j = tid + k * NT;
          const float* p = pbase + j * 5;
          const float x = p[0], y = p[1], z = p[2], w4 = p[3];
          s_k4[slot] = make_float4(x, y, z, w4);
          s_cc[slot] = ALPHA * (x*x + y*y + z*z + w4*w4) + mys[k];
          s_row4col[slot] = -1;
        }
      }
    }
    if (tid == 0) s_K = Ktot < KMAX ? Ktot : KMAX;
  }
  __syncthreads();
  const int K = s_K;

  // ---------- phase 4: row reduction (u = row minima of full cost) ----------
  {
    const float4 m2 = s_m2t[tid];
    const float  rc = s_rc[tid];
    float best = BIGF; int bj = 0;
    for (int slot = 0; slot < K; ++slot) {
      const float4 q = s_k4[slot];
      const float d = rc + s_cc[slot]
                    + m2.x*q.x + m2.y*q.y + m2.z*q.z + m2.w*q.w;
      if (d < best) { best = d; bj = slot; }
    }
    s_u[tid] = best;
    s_amin[tid] = (short)bj;
  }
  __syncthreads();

  // ---------- phase 4b: column reduction -> cp = cc + p, p = -colmin ----------
#pragma unroll
  for (int k = 0; k < SPT; ++k) {
    const int slot = tid + k * NT;
    if (slot < K) {
      const float4 q = s_k4[slot];
      const float cc = s_cc[slot];
      float best = BIGF; int br = -1;
      for (int i = 0; i < MTARG; ++i) {
        const float4 m2 = s_m2t[i];
        const float d = s_rc[i] + cc - s_u[i]
                      + m2.x*q.x + m2.y*q.y + m2.z*q.z + m2.w*q.w;
        if (d < best) { best = d; br = i; }
      }
      s_cp[slot] = cc - best;
      s_argr[slot] = (short)br;
    } else if (slot < KMAX) {
      s_cp[slot] = BIGF;
      s_argr[slot] = -1;
    }
  }
  __syncthreads();

  // ---------- phase 4c: greedy tight matching (parallel, deterministic) ----------
  atomicMin(&s_bC[(int)s_amin[tid]], tid);
  __syncthreads();
#pragma unroll
  for (int k = 0; k < SPT; ++k) {
    const int j = tid + k * NT;
    if (j < K) {
      const int w = s_bC[j];
      if (w != IINF) { s_row4col[j] = (short)w; s_col4row[w] = (short)j; }
    }
  }
  __syncthreads();
#pragma unroll
  for (int k = 0; k < SPT; ++k) {
    const int j = tid + k * NT;
    if (j < K && s_row4col[j] < 0) {
      const int r = (int)s_argr[j];
      if (r >= 0 && s_col4row[r] < 0) atomicMin(&s_bR[r], j);
    }
  }
  __syncthreads();
  {
    const int j = s_bR[tid];
    if (s_col4row[tid] < 0 && j != IINF) {
      s_col4row[tid] = (short)j;
      s_row4col[j] = (short)tid;
    }
  }
  __syncthreads();

  // ---------- phase 5: single-wave auction, adaptive groups, register masks ----------
  if (tid < 64) {
    // unassigned-row masks, register-resident (wave-uniform)
    unsigned long long um0 = __ballot(s_col4row[lane      ] < 0);
    unsigned long long um1 = __ballot(s_col4row[lane + 64 ] < 0);
    unsigned long long um2 = __ballot(s_col4row[lane + 128] < 0);
    unsigned long long um3 = __ballot(s_col4row[lane + 192] < 0);

    for (int round = 0; round < MAXROUND; ++round) {
      const int c0 = (int)__popcll(um0), c1 = (int)__popcll(um1);
      const int c2 = (int)__popcll(um2), c3 = (int)__popcll(um3);
      const int U = c0 + c1 + c2 + c3;
      if (U == 0) break;
      const int nb = U < 8 ? U : 8;
      const int lg = 31 - __builtin_clz(64 / nb);  // G = 64,32,16,16,8,8,8,8
      const int G  = 1 << lg;
      const int g  = lane >> lg;
      const int l  = lane & (G - 1);

      // group g serves the g-th unassigned row (global index order)
      int r = -1;
      if (g < nb) {
        int rem = g; unsigned long long mm; int base;
        if (rem < c0)            { mm = um0; base = 0; }
        else if (rem < c0+c1)    { mm = um1; base = 64;  rem -= c0; }
        else if (rem < c0+c1+c2) { mm = um2; base = 128; rem -= c0 + c1; }
        else                     { mm = um3; base = 192; rem -= c0 + c1 + c2; }
        int pos = 0;
#pragma unroll
        for (int w = 32; w >= 1; w >>= 1) {
          const unsigned long long msk = ((1ull << w) - 1ull) << pos;
          const int cw = (int)__popcll(mm & msk);
          if (rem >= cw) { rem -= cw; pos += w; }
        }
        r = base + pos;
      }

      // strided scan + top-2 butterfly over the G group lanes
      int j1 = -1;
      unsigned long long bkey = 0ull;
      if (r >= 0) {
        const float4 mt = s_m2t[r];
        unsigned long long key = ~0ull;
        unsigned int w2u = 0xFFFFFFFFu;
        for (int j = l; j < K; j += G) {
          const float4 q4 = s_k4[j];
          const float v = s_cp[j]
                        + mt.x*q4.x + mt.y*q4.y + mt.z*q4.z + mt.w*q4.w;
          const unsigned long long k2 =
              ((unsigned long long)ordf(v) << 32) | (unsigned int)j;
          if (k2 < key) { w2u = (unsigned int)(key >> 32); key = k2; }
          else { const unsigned int o = (unsigned int)(k2 >> 32); if (o < w2u) w2u = o; }
        }
        for (int off = 1; off < G; off <<= 1) {
          const unsigned long long ok = __shfl_xor(key, off);
          const unsigned int ow2 = __shfl_xor(w2u, off);
          if (ok < key) {
            const unsigned int v1 = (unsigned int)(key >> 32);
            w2u = (ow2 < v1) ? ow2 : v1;
            key = ok;
          } else {
            const unsigned int o1 = (unsigned int)(ok >> 32);
            if (o1 < w2u) w2u = o1;
          }
        }
        if (l == 0) {
          j1 = (int)(key & 0xFFFFFFFFull);
          const float ncp = s_cp[j1]
                          + (unordf(w2u) - unordf((unsigned int)(key >> 32))) + EPSA;
          bkey = ((unsigned long long)ordf(ncp) << 32) | (unsigned int)r;
        }
      }

      // broadcast proposals to ALL lanes (static 8-slot unroll)
      int Jv[8]; unsigned long long Bv[8]; int Rv[8];
#pragma unroll
      for (int g2 = 0; g2 < 8; ++g2) {
        const int src = (g2 << lg) & 63;
        Jv[g2] = __shfl(j1, src);
        Bv[g2] = __shfl(bkey, src);
        Rv[g2] = __shfl(r, src);
        if (g2 >= nb) { Jv[g2] = -1; Bv[g2] = 0ull; Rv[g2] = -1; }
      }

      // winner per column (uniform across lanes; keys unique via row low bits)
      bool win[8];
#pragma unroll
      for (int g2 = 0; g2 < 8; ++g2) {
        bool w = (Jv[g2] >= 0);
#pragma unroll
        for (int g3 = 0; g3 < 8; ++g3)
          if (g3 != g2 && Jv[g3] == Jv[g2] && Bv[g3] > Bv[g2]) w = false;
        win[g2] = w;
      }

      // per-lane slot select (static indexing only)
      bool mywin = false; int myJ = -1, myR = -1;
      unsigned long long myB = 0ull;
#pragma unroll
      for (int g2 = 0; g2 < 8; ++g2)
        if (lane == g2) { mywin = win[g2]; myJ = Jv[g2]; myR = Rv[g2]; myB = Bv[g2]; }

      // parallel eviction read + broadcast
      int oldv = -1;
      if (mywin && myJ >= 0) oldv = (int)s_row4col[myJ];
      int Ov[8];
#pragma unroll
      for (int g2 = 0; g2 < 8; ++g2) Ov[g2] = __shfl(oldv, g2);

      // distributed winner writes (distinct cells per lane)
      if (mywin && myJ >= 0) {
        s_cp[myJ] = unordf((unsigned int)(myB >> 32));
        s_row4col[myJ] = (short)myR;
        s_col4row[myR] = (short)myJ;
        if (oldv >= 0) s_col4row[oldv] = -1;
      }

      // register mask update (uniform on all lanes)
#pragma unroll
      for (int g2 = 0; g2 < 8; ++g2) {
        if (win[g2] && Jv[g2] >= 0) {
          const int rr = Rv[g2];
          const unsigned long long rb = 1ull << (rr & 63);
          if (rr < 64)       um0 &= ~rb;
          else if (rr < 128) um1 &= ~rb;
          else if (rr < 192) um2 &= ~rb;
          else               um3 &= ~rb;
          const int oo = Ov[g2];
          if (oo >= 0) {
            const unsigned long long ob = 1ull << (oo & 63);
            if (oo < 64)       um0 |= ob;
            else if (oo < 128) um1 |= ob;
            else if (oo < 192) um2 |= ob;
            else               um3 |= ob;
          }
        }
      }
      __threadfence_block();
    }
    // safety fallback (unreachable in practice)
    if (lane == 0) {
      for (int i = 0; i < MTARG; ++i) {
        if (s_col4row[i] < 0) {
          for (int j = 0; j < K; ++j)
            if (s_row4col[j] < 0) { s_row4col[j] = (short)i; s_col4row[i] = (short)j; break; }
        }
      }
    }
  }
  __syncthreads();

  // ---------- phase 6: loss = sum matched full costs - sum lca ----------
  float acc;
  {
    const int j = (int)s_col4row[tid];
    const float4 q = s_k4[j];
    const float4 m2 = s_m2t[tid];
    acc = s_rc[tid] + s_cc[j]
        + m2.x*q.x + m2.y*q.y + m2.z*q.z + m2.w*q.w;
  }
#pragma unroll
  for (int off = 32; off > 0; off >>= 1) acc += __shfl_down(acc, off);
  __syncthreads();
  if (lane == 0) s_scr[wave] = acc;
  __syncthreads();
  if (tid == 0) {
    float s = 0.0f;
    for (int w = 0; w < NW; ++w) s += s_scr[w];
    out[0] = s - s_sumlca;
  }
}

extern "C" void kernel_launch(void* const* d_in, const int* in_sizes, int n_in,
                              void* d_out, int out_size, void* d_ws, size_t ws_size,
                              hipStream_t stream) {
  const float* pred  = (const float*)d_in[0];
  const float* label = (const float*)d_in[1];
  float* out = (float*)d_out;
  hipLaunchKernelGGL(lap_loss_kernel, dim3(1), dim3(NT), 0, stream,
                     pred, label, out);
}